// Round 9
// baseline (1048.873 us; speedup 1.0000x reference)
//
#include <hip/hip_runtime.h>
#include <math.h>

typedef unsigned short u16;
typedef unsigned int u32;
typedef __attribute__((ext_vector_type(8))) short s8v;   // 8 bf16 (4 VGPR)
typedef __attribute__((ext_vector_type(4))) float f4v;   // mfma acc

// Problem constants
#define Bx 8
#define Cx 64
#define Nx 128
#define Tx 288
#define PL 12
#define CL 24
#define SP 12
#define TOUT 300
#define EPSV 0.01f
#define NTb 2359296L   // 8192*288 elems per batch

__device__ __forceinline__ float b2f(u16 h) {
  union { u32 u; float f; } v; v.u = ((u32)h) << 16; return v.f;
}
__device__ __forceinline__ u16 f2b(float f) {
  union { float f; u32 u; } v; v.f = f;
  return (u16)((v.u + 0x7FFFu + ((v.u >> 16) & 1u)) >> 16);  // RNE
}

// ---------------------------------------------------------------------------
// K0: adjacency  adjT[m][n] = softmax_m( emb[n]·emb[m] - 10*I ).  grid 128x64.
// ---------------------------------------------------------------------------
__global__ __launch_bounds__(64) void k0_adj(const float* __restrict__ emb,
                                             float* __restrict__ adjT) {
  int n = blockIdx.x;
  int lane = threadIdx.x;
  float d0 = 0.f, d1 = 0.f;
  for (int k = 0; k < 64; ++k) {
    float e = emb[n * 64 + k];
    d0 += e * emb[lane * 64 + k];
    d1 += e * emb[(lane + 64) * 64 + k];
  }
  if (lane == n) d0 -= 10.f;
  if (lane + 64 == n) d1 -= 10.f;
  float mx = fmaxf(d0, d1);
  for (int off = 32; off; off >>= 1) mx = fmaxf(mx, __shfl_xor(mx, off, 64));
  float e0 = expf(d0 - mx), e1 = expf(d1 - mx);
  float sm = e0 + e1;
  for (int off = 32; off; off >>= 1) sm += __shfl_xor(sm, off, 64);
  float inv = 1.f / sm;
  adjT[lane * 128 + n] = e0 * inv;
  adjT[(lane + 64) * 128 + n] = e1 * inv;
}

// ---------------------------------------------------------------------------
// Kw: weight prep (once), tiled for coalesced MFMA A-loads.
// ---------------------------------------------------------------------------
__global__ __launch_bounds__(256) void k_wprep(
    const float* __restrict__ cw1, const float* __restrict__ cw2,
    const float* __restrict__ rsw, const float* __restrict__ skw,
    u16* __restrict__ W16, u16* __restrict__ WR16, u16* __restrict__ WS16) {
  int R = blockIdx.x;
  const float* src = (R < 64) ? (cw1 + (long)R * 1664) : (cw2 + (long)(R - 64) * 1664);
  for (int k = threadIdx.x; k < 1664; k += 256) {
    int j = k >> 7;
    int rem = k & 127;
    int tap = rem >> 6, cc = rem & 63;
    int kc = rem >> 5;
    W16[(j * 4 + kc) * 4096 + R * 32 + (rem & 31)] = f2b(src[(j * 64 + cc) * 2 + tap]);
  }
  if (R < 64) {
    for (int k = threadIdx.x; k < 64; k += 256) {
      int h = k >> 5;
      WR16[(h * 64 + R) * 32 + (k & 31)] = f2b(rsw[R * 64 + k]);
      WS16[(h * 64 + R) * 32 + (k & 31)] = f2b(skw[R * 64 + k]);
    }
  }
}

// ---------------------------------------------------------------------------
// Kw2: pack residual-extrap weights to bf16, layout WJ16[(j*768+o)*768+q].
// ---------------------------------------------------------------------------
__global__ __launch_bounds__(256) void k_wprep2(
    const float* __restrict__ w0, const float* __restrict__ w1,
    const float* __restrict__ w2, const float* __restrict__ w3,
    u16* __restrict__ WJ16) {
  int idx0 = blockIdx.x * 256 + threadIdx.x;
  for (int idx = idx0; idx < 2359296; idx += 256 * 256) {
    int j = idx / 589824;
    int r = idx - j * 589824;
    const float* w = (j == 0) ? w0 : (j == 1) ? w1 : (j == 2) ? w2 : w3;
    WJ16[idx] = f2b(w[r]);
  }
}

// ---------------------------------------------------------------------------
// K1: per-series norm chain, group-fused. One wave/series; 4/block.
// ---------------------------------------------------------------------------
__global__ __launch_bounds__(256) void k1_chain(
    const float* __restrict__ xb, float* __restrict__ ltm, float* __restrict__ lts,
    float* __restrict__ pm, float* __restrict__ ps, u16* __restrict__ stm,
    u16* __restrict__ sts, u16* __restrict__ x3, u16* __restrict__ SG) {
  __shared__ float lds[4 * 352];
  int tid = threadIdx.x;
  int wv = tid >> 6, lane = tid & 63;
  float* buf = lds + wv * 352;
  float* pat = buf + 288;
  long s = (long)blockIdx.x * 4 + wv;
  const float* xs = xb + s * Tx;

  int b_loc = (int)(s >> 13);
  int cin = ((int)s >> 7) & 63;
  int n = (int)s & 127;
  long sg0 = (((long)b_loc * 4) * 128 + n) * 768 + cin * 12;

  float v[5];
  float sum = 0.f, sum2 = 0.f;
#pragma unroll
  for (int i = 0; i < 5; ++i) {
    int t = lane + 64 * i;
    if (t < Tx) { v[i] = xs[t]; sum += v[i]; sum2 += v[i] * v[i]; }
    else v[i] = 0.f;
  }
  for (int off = 32; off; off >>= 1) {
    sum += __shfl_xor(sum, off, 64);
    sum2 += __shfl_xor(sum2, off, 64);
  }
  float mean = sum * (1.f / 288.f);
  float var = sum2 * (1.f / 288.f) - mean * mean + 1e-5f;
  float sd = sqrtf(var);
  float r1 = rsqrtf(var + EPSV);
  if (lane == 0) { ltm[s] = mean; lts[s] = sd; }
#pragma unroll
  for (int i = 0; i < 5; ++i) {
    int t = lane + 64 * i;
    if (t < Tx) {
      float x1v = (v[i] - mean) * r1;
      v[i] = x1v;
      buf[t] = x1v;
      if (t >= Tx - SP) SG[sg0 + t - (Tx - SP)] = f2b(x1v);
    }
  }
  __syncthreads();
  if (lane < CL) {
    float a = 0.f, b2 = 0.f;
    for (int k = 0; k < 12; ++k) {
      float u = buf[k * CL + lane];
      a += u; b2 += u * u;
    }
    float pmv = a * (1.f / 12.f);
    float pvar = b2 * (1.f / 12.f) - pmv * pmv + 1e-5f;
    float psd = sqrtf(pvar);
    pat[lane] = pmv; pat[CL + lane] = psd;
    pm[s * CL + lane] = pmv; ps[s * CL + lane] = psd;
  }
  __syncthreads();
  float w2v[5];
#pragma unroll
  for (int i = 0; i < 5; ++i) {
    int t = lane + 64 * i;
    if (t < Tx) {
      int l = t % CL;
      float pmv = pat[l], psd = pat[CL + l];
      float x2v = (v[i] - pmv) * rsqrtf(psd * psd + EPSV);
      w2v[i] = x2v;
      if (t >= Tx - SP) SG[sg0 + 98304 + t - (Tx - SP)] = f2b(x2v);
    } else w2v[i] = 0.f;
  }
  __syncthreads();
#pragma unroll
  for (int i = 0; i < 5; ++i) {
    int t = lane + 64 * i;
    if (t < Tx) buf[t] = w2v[i];
  }
  __syncthreads();
#pragma unroll
  for (int i = 0; i < 5; ++i) {
    int t = lane + 64 * i;
    if (t < Tx) {
      int te = t < 11 ? 11 : t;
      float a = 0.f, b2 = 0.f;
#pragma unroll
      for (int jj = 0; jj < 12; ++jj) {
        float u = buf[te - 11 + jj];
        a += u; b2 += u * u;
      }
      float m = a * (1.f / 12.f);
      float varw = b2 * (1.f / 12.f) - m * m + 1e-5f;
      stm[s * Tx + t] = f2b(m);
      sts[s * Tx + t] = f2b(sqrtf(varw));
      u16 xb3 = f2b((w2v[i] - m) * rsqrtf(varw + EPSV));
      x3[s * Tx + t] = xb3;
      if (t >= Tx - SP) SG[sg0 + 2 * 98304 + t - (Tx - SP)] = xb3;
    }
  }
}

// ---------------------------------------------------------------------------
// K2: spatial norm, group-fused. grid g*576 x 128 (c_ext = bid/9).
// Packed uint4 stores; also emits SG j=3 tail.
// ---------------------------------------------------------------------------
__global__ __launch_bounds__(128) void k2_spatial(
    const u16* __restrict__ x3, const float* __restrict__ adjT,
    u16* __restrict__ x4, u16* __restrict__ spm, u16* __restrict__ sps,
    u16* __restrict__ SG) {
  __shared__ float X[128 * 36];
  int bid = blockIdx.x;
  int tc = bid % 9;
  long c = bid / 9;
  int t0 = tc * 32;
  int tid = threadIdx.x;
  for (int idx = tid; idx < 128 * 32; idx += 128) {
    int m = idx >> 5, i = idx & 31;
    X[m * 36 + i] = b2f(x3[(c * 128 + m) * Tx + t0 + i]);
  }
  __syncthreads();
  float a1[32], a2[32];
#pragma unroll
  for (int i = 0; i < 32; ++i) { a1[i] = 0.f; a2[i] = 0.f; }
  for (int m = 0; m < 128; ++m) {
    float a = adjT[m * 128 + tid];
    const float4* xp = (const float4*)&X[m * 36];
#pragma unroll
    for (int ii = 0; ii < 8; ++ii) {
      float4 xq = xp[ii];
      float t0v = a * xq.x; a1[ii * 4 + 0] += t0v; a2[ii * 4 + 0] += t0v * xq.x;
      float t1v = a * xq.y; a1[ii * 4 + 1] += t1v; a2[ii * 4 + 1] += t1v * xq.y;
      float t2v = a * xq.z; a1[ii * 4 + 2] += t2v; a2[ii * 4 + 2] += t2v * xq.z;
      float t3v = a * xq.w; a1[ii * 4 + 3] += t3v; a2[ii * 4 + 3] += t3v * xq.w;
    }
  }
  long sOut = c * 128 + tid;
  u32 xw[16], mw[16], sw[16];
#pragma unroll
  for (int p = 0; p < 16; ++p) {
    u32 xl = 0, ml = 0, sl = 0;
#pragma unroll
    for (int h = 0; h < 2; ++h) {
      int i = p * 2 + h;
      float mean = a1[i];
      float varv = a2[i] - mean * mean + 1e-5f;
      float xv = X[tid * 36 + i];
      xl |= ((u32)f2b((xv - mean) * rsqrtf(varv + EPSV))) << (16 * h);
      ml |= ((u32)f2b(mean)) << (16 * h);
      sl |= ((u32)f2b(sqrtf(varv))) << (16 * h);
    }
    xw[p] = xl; mw[p] = ml; sw[p] = sl;
  }
  long base = sOut * Tx + t0;
  uint4* xd = (uint4*)(x4 + base);
  uint4* md = (uint4*)(spm + base);
  uint4* sd = (uint4*)(sps + base);
#pragma unroll
  for (int k = 0; k < 4; ++k) {
    uint4 a, b, d;
    a.x = xw[k * 4]; a.y = xw[k * 4 + 1]; a.z = xw[k * 4 + 2]; a.w = xw[k * 4 + 3];
    b.x = mw[k * 4]; b.y = mw[k * 4 + 1]; b.z = mw[k * 4 + 2]; b.w = mw[k * 4 + 3];
    d.x = sw[k * 4]; d.y = sw[k * 4 + 1]; d.z = sw[k * 4 + 2]; d.w = sw[k * 4 + 3];
    xd[k] = a; md[k] = b; sd[k] = d;
  }
  if (tc == 8) {   // t=276..287 live in pairs 10..15
    long sg = (((c >> 6) * 4 + 3) * 128 + tid) * 768 + (long)(c & 63) * 12;
    u32* sp = (u32*)(SG + sg);
#pragma unroll
    for (int k = 0; k < 6; ++k) sp[k] = xw[10 + k];
  }
}

// ---------------------------------------------------------------------------
// K3 (MFMA): tails GEMM. Per (b_loc,j): out[128n][768o] = S[n][q] . W[o][q] + b.
// ---------------------------------------------------------------------------
__global__ __launch_bounds__(256) void k3_mfma(
    const u16* __restrict__ SG, const u16* __restrict__ WJ16,
    const float* __restrict__ bb0, const float* __restrict__ bb1,
    const float* __restrict__ bb2, const float* __restrict__ bb3,
    u16* __restrict__ tails) {
  __shared__ u16 Al[64 * 40];
  __shared__ u16 Bl[128 * 40];
  int bid = blockIdx.x;
  int ot = bid % 6;
  int rest = bid / 6;
  int nt = rest & 1;
  int bj = rest >> 1;            // b_loc*4 + j
  int j = bj & 3;
  int tid = threadIdx.x;
  int wv = tid >> 6, lane = tid & 63;
  int wo = wv & 1, wm = wv >> 1;
  int rlane = lane & 15, glane = lane >> 4;
  int klane = glane * 8;

  const float* Bv = (j == 0) ? bb0 : (j == 1) ? bb1 : (j == 2) ? bb2 : bb3;
  const u16* Abase = SG + (long)bj * 98304 + (long)(nt * 64) * 768;
  const u16* Wbase = WJ16 + (long)j * 589824 + (long)(ot * 128) * 768;

  f4v acc[2][4];
#pragma unroll
  for (int ct = 0; ct < 4; ++ct) {
    float bvv = Bv[ot * 128 + wo * 64 + ct * 16 + rlane];
#pragma unroll
    for (int rt = 0; rt < 2; ++rt)
#pragma unroll
      for (int reg = 0; reg < 4; ++reg) acc[rt][ct][reg] = bvv;
  }

  int srow = tid >> 2, sseg = tid & 3;     // staging assignment
  for (int ks = 0; ks < 24; ++ks) {
    int q0 = ks * 32;
    __syncthreads();
    *(float4*)(Al + srow * 40 + sseg * 8) =
        *(const float4*)(Abase + (long)srow * 768 + q0 + sseg * 8);
    *(float4*)(Bl + srow * 40 + sseg * 8) =
        *(const float4*)(Wbase + (long)srow * 768 + q0 + sseg * 8);
    *(float4*)(Bl + (srow + 64) * 40 + sseg * 8) =
        *(const float4*)(Wbase + (long)(srow + 64) * 768 + q0 + sseg * 8);
    __syncthreads();
    s8v av[2], bv[4];
#pragma unroll
    for (int rt = 0; rt < 2; ++rt)
      av[rt] = *(const s8v*)(Al + (wm * 32 + rt * 16 + rlane) * 40 + klane);
#pragma unroll
    for (int ct = 0; ct < 4; ++ct)
      bv[ct] = *(const s8v*)(Bl + (wo * 64 + ct * 16 + rlane) * 40 + klane);
#pragma unroll
    for (int rt = 0; rt < 2; ++rt)
#pragma unroll
      for (int ct = 0; ct < 4; ++ct)
        acc[rt][ct] = __builtin_amdgcn_mfma_f32_16x16x32_bf16(av[rt], bv[ct], acc[rt][ct], 0, 0, 0);
  }

  long outbase = (long)bj * 98304;  // 128*768 per (b,j)
#pragma unroll
  for (int rt = 0; rt < 2; ++rt) {
    int nn = nt * 64 + wm * 32 + rt * 16 + glane * 4;
#pragma unroll
    for (int ct = 0; ct < 4; ++ct) {
      int o = ot * 128 + wo * 64 + ct * 16 + rlane;
#pragma unroll
      for (int reg = 0; reg < 4; ++reg)
        tails[outbase + (long)(nn + reg) * 768 + o] = f2b(acc[rt][ct][reg]);
    }
  }
}

// ---------------------------------------------------------------------------
// k4 staging, strip form.  Bs[u][cc] (stride 72 u16), u in 0..32,
// value = xcat[j][cc][t0-1+u].  256 threads = 32 cc-pairs x 8 strips of
// 4 aligned tg (tg0 = t0+4*ut, rows u=4*ut+1..4*ut+4); u=0 edge by tid<32.
// Fast path (chunks 0..8): one vector load per row, addr calc amortized x4.
// ---------------------------------------------------------------------------
template<int MODE>
__device__ __forceinline__ u32 eval_one(
    const u16* __restrict__ T, const float* __restrict__ Tf,
    const float* __restrict__ fm, const float* __restrict__ fs,
    const float* __restrict__ fpm, const float* __restrict__ fps,
    const u16* __restrict__ tl, int n, int cc0, int tg) {
  u32 w = 0;
  if (MODE == 0) {
    if ((unsigned)tg < (unsigned)TOUT) {
      int tcl = tg < Tx ? tg : Tx - 1;
      const u16* p = T + ((long)cc0 * 128 + n) * Tx + tcl;
      w = (u32)p[0] | ((u32)p[128 * Tx] << 16);
    }
  } else if (MODE == 1) {
    if ((unsigned)tg < (unsigned)Tx) {
      const u16* p = T + ((long)cc0 * 128 + n) * Tx + tg;
      w = (u32)p[0] | ((u32)p[128 * Tx] << 16);
    } else if (tg >= Tx && tg < TOUT) {
      w = *(const u32*)(tl + (long)n * 768 + (tg - Tx) * 64 + cc0);
    }
  } else if (MODE == 2) {
    if ((unsigned)tg < (unsigned)TOUT)
      w = (u32)f2b(Tf[cc0 * 128 + n]) | ((u32)f2b(Tf[(cc0 + 1) * 128 + n]) << 16);
  } else if (MODE == 3) {
    if ((unsigned)tg < (unsigned)TOUT) {
      int l = tg % CL;
      w = (u32)f2b(Tf[((long)cc0 * 128 + n) * CL + l]) |
          ((u32)f2b(Tf[((long)(cc0 + 1) * 128 + n) * CL + l]) << 16);
    }
  } else if (MODE == 4) {
    if ((unsigned)tg < (unsigned)TOUT) {
      int tcl = tg < Tx ? tg : Tx - 1;
      const float* p = Tf + ((long)cc0 * 128 + n) * Tx + tcl;
      w = (u32)f2b(p[0]) | ((u32)f2b(p[128 * Tx]) << 16);
    }
  } else if (MODE == 5) {
    if ((unsigned)tg < (unsigned)Tx) {
      long s0 = (long)cc0 * 128 + n, s1 = s0 + 128;
      float v0 = (Tf[s0 * Tx + tg] - fm[s0]) * rsqrtf(fs[s0] * fs[s0] + EPSV);
      float v1 = (Tf[s1 * Tx + tg] - fm[s1]) * rsqrtf(fs[s1] * fs[s1] + EPSV);
      w = (u32)f2b(v0) | ((u32)f2b(v1) << 16);
    } else if (tg >= Tx && tg < TOUT) {
      w = *(const u32*)(tl + (long)n * 768 + (tg - Tx) * 64 + cc0);
    }
  } else {  // MODE 6
    if ((unsigned)tg < (unsigned)Tx) {
      long s0 = (long)cc0 * 128 + n, s1 = s0 + 128;
      int l = tg % CL;
      float x10 = (Tf[s0 * Tx + tg] - fm[s0]) * rsqrtf(fs[s0] * fs[s0] + EPSV);
      float x11 = (Tf[s1 * Tx + tg] - fm[s1]) * rsqrtf(fs[s1] * fs[s1] + EPSV);
      float p0 = fpm[s0 * CL + l], q0 = fps[s0 * CL + l];
      float p1 = fpm[s1 * CL + l], q1 = fps[s1 * CL + l];
      float v0 = (x10 - p0) * rsqrtf(q0 * q0 + EPSV);
      float v1 = (x11 - p1) * rsqrtf(q1 * q1 + EPSV);
      w = (u32)f2b(v0) | ((u32)f2b(v1) << 16);
    } else if (tg >= Tx && tg < TOUT) {
      w = *(const u32*)(tl + (long)n * 768 + (tg - Tx) * 64 + cc0);
    }
  }
  return w;
}

template<int MODE>
__device__ __forceinline__ void stage_j(
    u16* __restrict__ Bb, const u16* __restrict__ T,
    const float* __restrict__ Tf, const float* __restrict__ fm,
    const float* __restrict__ fs, const float* __restrict__ fpm,
    const float* __restrict__ fps, const u16* __restrict__ tl,
    int n, int t0, int tid) {
  int ccp = tid >> 3, ut = tid & 7;
  int cc0 = ccp * 2;
  int tg0 = t0 + ut * 4;                       // multiple of 4 -> aligned loads
  u16* dst = Bb + (ut * 4 + 1) * 72 + cc0;     // rows u = 4*ut+1 .. 4*ut+4
  if (tg0 + 3 < Tx) {                          // chunks 0..8: always fast
    u32 w0, w1, w2, w3;
    if (MODE == 0 || MODE == 1) {
      const u16* p = T + ((long)cc0 * 128 + n) * Tx + tg0;
      uint2 a = *(const uint2*)p;
      uint2 b = *(const uint2*)(p + 128 * Tx);
      w0 = (a.x & 0xFFFFu) | (b.x << 16);
      w1 = (a.x >> 16) | (b.x & 0xFFFF0000u);
      w2 = (a.y & 0xFFFFu) | (b.y << 16);
      w3 = (a.y >> 16) | (b.y & 0xFFFF0000u);
    } else if (MODE == 2) {
      u32 wv = (u32)f2b(Tf[cc0 * 128 + n]) | ((u32)f2b(Tf[(cc0 + 1) * 128 + n]) << 16);
      w0 = wv; w1 = wv; w2 = wv; w3 = wv;
    } else if (MODE == 3) {
      int la = tg0 % CL;
      int lb = la + 1 - ((la + 1 >= CL) ? CL : 0);
      int lc = la + 2 - ((la + 2 >= CL) ? CL : 0);
      int ld = la + 3 - ((la + 3 >= CL) ? CL : 0);
      const float* p0 = Tf + ((long)cc0 * 128 + n) * CL;
      const float* p1 = p0 + 128L * CL;
      w0 = (u32)f2b(p0[la]) | ((u32)f2b(p1[la]) << 16);
      w1 = (u32)f2b(p0[lb]) | ((u32)f2b(p1[lb]) << 16);
      w2 = (u32)f2b(p0[lc]) | ((u32)f2b(p1[lc]) << 16);
      w3 = (u32)f2b(p0[ld]) | ((u32)f2b(p1[ld]) << 16);
    } else if (MODE == 4) {
      const float* p = Tf + ((long)cc0 * 128 + n) * Tx + tg0;
      float4 a = *(const float4*)p;
      float4 b = *(const float4*)(p + 128 * Tx);
      w0 = (u32)f2b(a.x) | ((u32)f2b(b.x) << 16);
      w1 = (u32)f2b(a.y) | ((u32)f2b(b.y) << 16);
      w2 = (u32)f2b(a.z) | ((u32)f2b(b.z) << 16);
      w3 = (u32)f2b(a.w) | ((u32)f2b(b.w) << 16);
    } else if (MODE == 5) {
      long s0 = (long)cc0 * 128 + n, s1 = s0 + 128;
      float4 a = *(const float4*)(Tf + s0 * Tx + tg0);
      float4 b = *(const float4*)(Tf + s1 * Tx + tg0);
      float m0 = fm[s0], r0 = rsqrtf(fs[s0] * fs[s0] + EPSV);
      float m1 = fm[s1], r1 = rsqrtf(fs[s1] * fs[s1] + EPSV);
      w0 = (u32)f2b((a.x - m0) * r0) | ((u32)f2b((b.x - m1) * r1) << 16);
      w1 = (u32)f2b((a.y - m0) * r0) | ((u32)f2b((b.y - m1) * r1) << 16);
      w2 = (u32)f2b((a.z - m0) * r0) | ((u32)f2b((b.z - m1) * r1) << 16);
      w3 = (u32)f2b((a.w - m0) * r0) | ((u32)f2b((b.w - m1) * r1) << 16);
    } else {  // MODE 6
      long s0 = (long)cc0 * 128 + n, s1 = s0 + 128;
      float4 a = *(const float4*)(Tf + s0 * Tx + tg0);
      float4 b = *(const float4*)(Tf + s1 * Tx + tg0);
      float m0 = fm[s0], r0 = rsqrtf(fs[s0] * fs[s0] + EPSV);
      float m1 = fm[s1], r1 = rsqrtf(fs[s1] * fs[s1] + EPSV);
      int la = tg0 % CL;
      int lb = la + 1 - ((la + 1 >= CL) ? CL : 0);
      int lc = la + 2 - ((la + 2 >= CL) ? CL : 0);
      int ld = la + 3 - ((la + 3 >= CL) ? CL : 0);
      const float* pm0 = fpm + s0 * CL; const float* qs0 = fps + s0 * CL;
      const float* pm1 = fpm + s1 * CL; const float* qs1 = fps + s1 * CL;
      float xa0 = (a.x - m0) * r0, xa1 = (a.y - m0) * r0, xa2 = (a.z - m0) * r0, xa3 = (a.w - m0) * r0;
      float ya0 = (b.x - m1) * r1, ya1 = (b.y - m1) * r1, ya2 = (b.z - m1) * r1, ya3 = (b.w - m1) * r1;
      w0 = (u32)f2b((xa0 - pm0[la]) * rsqrtf(qs0[la] * qs0[la] + EPSV)) |
           ((u32)f2b((ya0 - pm1[la]) * rsqrtf(qs1[la] * qs1[la] + EPSV)) << 16);
      w1 = (u32)f2b((xa1 - pm0[lb]) * rsqrtf(qs0[lb] * qs0[lb] + EPSV)) |
           ((u32)f2b((ya1 - pm1[lb]) * rsqrtf(qs1[lb] * qs1[lb] + EPSV)) << 16);
      w2 = (u32)f2b((xa2 - pm0[lc]) * rsqrtf(qs0[lc] * qs0[lc] + EPSV)) |
           ((u32)f2b((ya2 - pm1[lc]) * rsqrtf(qs1[lc] * qs1[lc] + EPSV)) << 16);
      w3 = (u32)f2b((xa3 - pm0[ld]) * rsqrtf(qs0[ld] * qs0[ld] + EPSV)) |
           ((u32)f2b((ya3 - pm1[ld]) * rsqrtf(qs1[ld] * qs1[ld] + EPSV)) << 16);
    }
    *(u32*)(dst) = w0;
    *(u32*)(dst + 72) = w1;
    *(u32*)(dst + 144) = w2;
    *(u32*)(dst + 216) = w3;
  } else {                                     // chunk 9 tail region
#pragma unroll 1
    for (int k = 0; k < 4; ++k)
      *(u32*)(dst + 72 * k) =
          eval_one<MODE>(T, Tf, fm, fs, fpm, fps, tl, n, cc0, tg0 + k);
  }
  if (tid < 32)                                // edge row u=0 (tg = t0-1)
    *(u32*)(Bb + tid * 2) =
        eval_one<MODE>(T, Tf, fm, fs, fpm, fps, tl, n, tid * 2, t0 - 1);
}

// ---------------------------------------------------------------------------
// K4 (MFMA), group-fused: M=128 rows x N=32 t x K=1664 per block + epilogue.
// Strip-vectorized staging (1 strip/thread, no loop); single-tap B [33][72];
// double-buffered; LDS 9504 B.
// ---------------------------------------------------------------------------
__global__ __launch_bounds__(256) void k4_mfma(
    const float* __restrict__ xbG, const float* __restrict__ ltmG,
    const float* __restrict__ ltsG, const float* __restrict__ pmG,
    const float* __restrict__ psG, const u16* __restrict__ stmG,
    const u16* __restrict__ stsG, const u16* __restrict__ x3G,
    const u16* __restrict__ x4G, const u16* __restrict__ spmG,
    const u16* __restrict__ spsG, const u16* __restrict__ tailsG,
    const u16* __restrict__ W16, const u16* __restrict__ WR16,
    const u16* __restrict__ WS16, const float* __restrict__ cb1,
    const float* __restrict__ cb2, const float* __restrict__ rsb,
    const float* __restrict__ skb,
    float* __restrict__ outXZG, float* __restrict__ outSG) {
  __shared__ __align__(16) unsigned char smemraw[9504];
  u16* Bs0 = (u16*)smemraw;                  // [33][72] bf16 (4752 B)
  u16* Bs1 = (u16*)(smemraw + 4752);         // [33][72] bf16
  u16* abuf = (u16*)smemraw;                 // epilogue [64][36] bf16 (4608 B)
  u16* zB = (u16*)(smemraw + 4608);          // epilogue [32][72] bf16 (4608 B)

  int bid = blockIdx.x;
  int n = bid & 127;
  int q = bid >> 7;
  int b_loc = q / 10;
  int chunk = q - b_loc * 10;                // 0..9
  int t0 = chunk * 32;
  int tid = threadIdx.x;
  int wv = tid >> 6, lane = tid & 63;
  int rlane = lane & 15, glane = lane >> 4;
  int klane = glane * 8;

  const float* xb  = xbG + b_loc * NTb;
  const float* ltm = ltmG + (long)b_loc * 8192;
  const float* lts = ltsG + (long)b_loc * 8192;
  const float* pm  = pmG + (long)b_loc * 196608;
  const float* ps  = psG + (long)b_loc * 196608;
  const u16* stm = stmG + b_loc * NTb;
  const u16* sts = stsG + b_loc * NTb;
  const u16* x3  = x3G + b_loc * NTb;
  const u16* x4  = x4G + b_loc * NTb;
  const u16* spm = spmG + b_loc * NTb;
  const u16* sps = spsG + b_loc * NTb;
  const u16* tails = tailsG + (long)b_loc * 393216;
  float* outXZ = outXZG + b_loc * NTb;
  float* outS  = outSG + (long)b_loc * 8192 * PL;

  f4v acc[2][2];
#pragma unroll
  for (int rt = 0; rt < 2; ++rt) {
    int Rb = wv * 32 + rt * 16 + glane * 4;
#pragma unroll
    for (int reg = 0; reg < 4; ++reg) {
      int R = Rb + reg;
      float bv = (R < 64) ? cb1[R] : cb2[R - 64];
#pragma unroll
      for (int ct = 0; ct < 2; ++ct) acc[rt][ct][reg] = bv;
    }
  }

  u16* bs = Bs0;
  u16* bo = Bs1;
  // prologue: stage j=0 (xb, f32 path)
  stage_j<4>(bs, (const u16*)0, xb, 0, 0, 0, 0, (const u16*)0, n, t0, tid);

  for (int j = 0; j < 13; ++j) {
    __syncthreads();
    // stage next j into the other buffer (overlaps with MFMA below)
    switch (j + 1) {
      case 1:  stage_j<5>(bo, 0, xb, ltm, lts, 0, 0, tails, n, t0, tid); break;
      case 2:  stage_j<2>(bo, 0, ltm, 0, 0, 0, 0, 0, n, t0, tid); break;
      case 3:  stage_j<2>(bo, 0, lts, 0, 0, 0, 0, 0, n, t0, tid); break;
      case 4:  stage_j<6>(bo, 0, xb, ltm, lts, pm, ps, tails + 98304, n, t0, tid); break;
      case 5:  stage_j<3>(bo, 0, pm, 0, 0, 0, 0, 0, n, t0, tid); break;
      case 6:  stage_j<3>(bo, 0, ps, 0, 0, 0, 0, 0, n, t0, tid); break;
      case 7:  stage_j<1>(bo, x3, 0, 0, 0, 0, 0, tails + 2 * 98304, n, t0, tid); break;
      case 8:  stage_j<0>(bo, stm, 0, 0, 0, 0, 0, 0, n, t0, tid); break;
      case 9:  stage_j<0>(bo, sts, 0, 0, 0, 0, 0, 0, n, t0, tid); break;
      case 10: stage_j<1>(bo, x4, 0, 0, 0, 0, 0, tails + 3 * 98304, n, t0, tid); break;
      case 11: stage_j<0>(bo, spm, 0, 0, 0, 0, 0, 0, n, t0, tid); break;
      case 12: stage_j<0>(bo, sps, 0, 0, 0, 0, 0, 0, n, t0, tid); break;
      default: break;                        // j==12: nothing left to stage
    }
    // MFMA on current buffer: kc 0,1 = tap0 (row tl), kc 2,3 = tap1 (row tl+1)
#pragma unroll
    for (int kc = 0; kc < 4; ++kc) {
      const u16* wj = W16 + (j * 4 + kc) * 4096;
      s8v av[2], bv[2];
#pragma unroll
      for (int rt = 0; rt < 2; ++rt) {
        int R = wv * 32 + rt * 16 + rlane;
        av[rt] = *(const s8v*)(wj + R * 32 + klane);
      }
#pragma unroll
      for (int ct = 0; ct < 2; ++ct) {
        int row = ct * 16 + rlane + (kc >> 1);
        bv[ct] = *(const s8v*)(bs + row * 72 + (kc & 1) * 32 + klane);
      }
#pragma unroll
      for (int rt = 0; rt < 2; ++rt)
#pragma unroll
        for (int ct = 0; ct < 2; ++ct)
          acc[rt][ct] = __builtin_amdgcn_mfma_f32_16x16x32_bf16(av[rt], bv[ct], acc[rt][ct], 0, 0, 0);
    }
    u16* tsw = bs; bs = bo; bo = tsw;
  }

  // ---- epilogue: waves 2,3 hold conv2 rows -> abuf (bf16); waves 0,1 make z ----
  __syncthreads();
  if (wv >= 2) {
#pragma unroll
    for (int rt = 0; rt < 2; ++rt)
#pragma unroll
      for (int ct = 0; ct < 2; ++ct)
#pragma unroll
        for (int reg = 0; reg < 4; ++reg) {
          int r = (wv - 2) * 32 + rt * 16 + glane * 4 + reg;
          int tl2 = ct * 16 + rlane;
          abuf[r * 36 + tl2] = f2b(acc[rt][ct][reg]);
        }
  }
  __syncthreads();
  if (wv < 2) {
#pragma unroll
    for (int rt = 0; rt < 2; ++rt)
#pragma unroll
      for (int ct = 0; ct < 2; ++ct)
#pragma unroll
        for (int reg = 0; reg < 4; ++reg) {
          int r = wv * 32 + rt * 16 + glane * 4 + reg;
          int tl2 = ct * 16 + rlane;
          float a2v = b2f(abuf[r * 36 + tl2]);
          float z = tanhf(acc[rt][ct][reg]) * (1.f / (1.f + expf(-a2v)));
          zB[tl2 * 72 + r] = f2b(z);
        }
  }
  __syncthreads();
  {
    int oL = wv * 16 + rlane;
    int oS = wv * 16 + glane * 4;
    s8v aR0 = *(const s8v*)(WR16 + oL * 32 + klane);
    s8v aR1 = *(const s8v*)(WR16 + 2048 + oL * 32 + klane);
    s8v aS0 = *(const s8v*)(WS16 + oL * 32 + klane);
    s8v aS1 = *(const s8v*)(WS16 + 2048 + oL * 32 + klane);
    for (int tt = 0; tt < 2; ++tt) {
      int tstart = t0 + tt * 16;
      if (tstart >= TOUT) break;
      bool res = tstart < Tx;
      s8v b0 = *(const s8v*)(zB + (tt * 16 + rlane) * 72 + klane);
      s8v b1 = *(const s8v*)(zB + (tt * 16 + rlane) * 72 + 32 + klane);
      f4v oa;
#pragma unroll
      for (int reg = 0; reg < 4; ++reg)
        oa[reg] = res ? rsb[oS + reg] : skb[oS + reg];
      if (res) {
        oa = __builtin_amdgcn_mfma_f32_16x16x32_bf16(aR0, b0, oa, 0, 0, 0);
        oa = __builtin_amdgcn_mfma_f32_16x16x32_bf16(aR1, b1, oa, 0, 0, 0);
        int tglob = tstart + rlane;
#pragma unroll
        for (int reg = 0; reg < 4; ++reg)
          outXZ[((long)(oS + reg) * 128 + n) * Tx + tglob] = oa[reg];
      } else {
        oa = __builtin_amdgcn_mfma_f32_16x16x32_bf16(aS0, b0, oa, 0, 0, 0);
        oa = __builtin_amdgcn_mfma_f32_16x16x32_bf16(aS1, b1, oa, 0, 0, 0);
        int tglob = tstart + rlane;
        if (tglob < TOUT) {
#pragma unroll
          for (int reg = 0; reg < 4; ++reg)
            outS[((long)(oS + reg) * 128 + n) * PL + (tglob - Tx)] = oa[reg];
        }
      }
    }
  }
}

// ---------------------------------------------------------------------------
extern "C" void kernel_launch(void* const* d_in, const int* in_sizes, int n_in,
                              void* d_out, int out_size, void* d_ws, size_t ws_size,
                              hipStream_t stream) {
  const float* x   = (const float*)d_in[0];
  const float* emb = (const float*)d_in[1];
  const float* rew[4] = {(const float*)d_in[2], (const float*)d_in[4],
                         (const float*)d_in[6], (const float*)d_in[8]};
  const float* reb[4] = {(const float*)d_in[3], (const float*)d_in[5],
                         (const float*)d_in[7], (const float*)d_in[9]};
  const float* c1w = (const float*)d_in[10];
  const float* c1b = (const float*)d_in[11];
  const float* c2w = (const float*)d_in[12];
  const float* c2b = (const float*)d_in[13];
  const float* skw = (const float*)d_in[14];
  const float* skb = (const float*)d_in[15];
  const float* rsw = (const float*)d_in[16];
  const float* rsb = (const float*)d_in[17];
  float* out = (float*)d_out;

  // shared region: adjT 64KB + W16 416KB + WR/WS 16KB + WJ16 4.5MB = 5,226,496 B
  const size_t shared_bytes = 65536 + (52 * 4096 + 2 * 4096) * 2 + 2359296UL * 2;
  // per-batch: f32 409600*4 + u16 (786432 + 6*NTb)*2 = 31,522,816 B
  const size_t per_batch = 409600UL * 4 + (786432UL + 6UL * 2359296UL) * 2;
  int g = 1;
  if (shared_bytes + 8 * per_batch + 4096 <= ws_size) g = 8;
  else if (shared_bytes + 4 * per_batch + 4096 <= ws_size) g = 4;
  else if (shared_bytes + 2 * per_batch + 4096 <= ws_size) g = 2;

  float* ws = (float*)d_ws;
  float* adjT = ws;                         // 16384 f32
  u16* W16  = (u16*)(adjT + 16384);         // 52*4096 u16
  u16* WR16 = W16 + 52 * 4096;              // 4096 u16
  u16* WS16 = WR16 + 4096;                  // 4096 u16
  u16* WJ16 = WS16 + 4096;                  // 4*768*768 u16
  float* fbase = (float*)(WJ16 + 2359296);
  float* ltm = fbase;                       // g*8192
  float* lts = ltm + (long)g * 8192;
  float* pmv = lts + (long)g * 8192;        // g*196608
  float* psv = pmv + (long)g * 196608;
  u16* tails16 = (u16*)(psv + (long)g * 196608);  // g*393216 u16
  u16* SGb = tails16 + (long)g * 393216;          // g*393216 u16
  u16* stm = SGb + (long)g * 393216;        // g*NTb each from here
  u16* sts = stm + (long)g * NTb;
  u16* x3  = sts + (long)g * NTb;
  u16* x4  = x3 + (long)g * NTb;
  u16* spm = x4 + (long)g * NTb;
  u16* sps = spm + (long)g * NTb;

  hipLaunchKernelGGL(k0_adj, dim3(128), dim3(64), 0, stream, emb, adjT);
  hipLaunchKernelGGL(k_wprep, dim3(128), dim3(256), 0, stream,
                     c1w, c2w, rsw, skw, W16, WR16, WS16);
  hipLaunchKernelGGL(k_wprep2, dim3(256), dim3(256), 0, stream,
                     rew[0], rew[1], rew[2], rew[3], WJ16);
  int ng = 8 / g;
  for (int gi = 0; gi < ng; ++gi) {
    long base = (long)gi * g;
    const float* xg = x + base * NTb;
    float* oXZ = out + base * NTb;
    float* oS  = out + (long)Bx * NTb + base * 8192 * PL;
    hipLaunchKernelGGL(k1_chain, dim3(g * 2048), dim3(256), 0, stream,
                       xg, ltm, lts, pmv, psv, stm, sts, x3, SGb);
    hipLaunchKernelGGL(k2_spatial, dim3(g * 576), dim3(128), 0, stream,
                       x3, adjT, x4, spm, sps, SGb);
    hipLaunchKernelGGL(k3_mfma, dim3(g * 48), dim3(256), 0, stream,
                       SGb, WJ16, reb[0], reb[1], reb[2], reb[3], tails16);
    hipLaunchKernelGGL(k4_mfma, dim3(g * 1280), dim3(256), 0, stream,
                       xg, ltm, lts, pmv, psv, stm, sts, x3, x4, spm, sps,
                       tails16, W16, WR16, WS16, c1b, c2b, rsb, skb, oXZ, oS);
  }
}

// Round 10
// 744.159 us; speedup vs baseline: 1.4095x; 1.4095x over previous
//
#include <hip/hip_runtime.h>
#include <math.h>

typedef unsigned short u16;
typedef unsigned int u32;
typedef __attribute__((ext_vector_type(8))) short s8v;   // 8 bf16 (4 VGPR)
typedef __attribute__((ext_vector_type(4))) float f4v;   // mfma acc

// Problem constants
#define Bx 8
#define Cx 64
#define Nx 128
#define Tx 288
#define PL 12
#define CL 24
#define SP 12
#define TOUT 300
#define EPSV 0.01f
#define NTb 2359296L   // 8192*288 elems per batch

__device__ __forceinline__ float b2f(u16 h) {
  union { u32 u; float f; } v; v.u = ((u32)h) << 16; return v.f;
}
__device__ __forceinline__ u16 f2b(float f) {
  union { float f; u32 u; } v; v.f = f;
  return (u16)((v.u + 0x7FFFu + ((v.u >> 16) & 1u)) >> 16);  // RNE
}

// ---------------------------------------------------------------------------
// K0: adjacency, bf16, layout adjB[n][m] = softmax_m( emb[n]·emb[m] - 10*I ).
// ---------------------------------------------------------------------------
__global__ __launch_bounds__(64) void k0_adj(const float* __restrict__ emb,
                                             u16* __restrict__ adjB) {
  int n = blockIdx.x;
  int lane = threadIdx.x;
  float d0 = 0.f, d1 = 0.f;
  for (int k = 0; k < 64; ++k) {
    float e = emb[n * 64 + k];
    d0 += e * emb[lane * 64 + k];
    d1 += e * emb[(lane + 64) * 64 + k];
  }
  if (lane == n) d0 -= 10.f;
  if (lane + 64 == n) d1 -= 10.f;
  float mx = fmaxf(d0, d1);
  for (int off = 32; off; off >>= 1) mx = fmaxf(mx, __shfl_xor(mx, off, 64));
  float e0 = expf(d0 - mx), e1 = expf(d1 - mx);
  float sm = e0 + e1;
  for (int off = 32; off; off >>= 1) sm += __shfl_xor(sm, off, 64);
  float inv = 1.f / sm;
  adjB[n * 128 + lane] = f2b(e0 * inv);
  adjB[n * 128 + lane + 64] = f2b(e1 * inv);
}

// ---------------------------------------------------------------------------
// Kw: weight prep (once), tiled for coalesced MFMA A-loads.
// ---------------------------------------------------------------------------
__global__ __launch_bounds__(256) void k_wprep(
    const float* __restrict__ cw1, const float* __restrict__ cw2,
    const float* __restrict__ rsw, const float* __restrict__ skw,
    u16* __restrict__ W16, u16* __restrict__ WR16, u16* __restrict__ WS16) {
  int R = blockIdx.x;
  const float* src = (R < 64) ? (cw1 + (long)R * 1664) : (cw2 + (long)(R - 64) * 1664);
  for (int k = threadIdx.x; k < 1664; k += 256) {
    int j = k >> 7;
    int rem = k & 127;
    int tap = rem >> 6, cc = rem & 63;
    int kc = rem >> 5;
    W16[(j * 4 + kc) * 4096 + R * 32 + (rem & 31)] = f2b(src[(j * 64 + cc) * 2 + tap]);
  }
  if (R < 64) {
    for (int k = threadIdx.x; k < 64; k += 256) {
      int h = k >> 5;
      WR16[(h * 64 + R) * 32 + (k & 31)] = f2b(rsw[R * 64 + k]);
      WS16[(h * 64 + R) * 32 + (k & 31)] = f2b(skw[R * 64 + k]);
    }
  }
}

// ---------------------------------------------------------------------------
// Kw2: pack residual-extrap weights to bf16, layout WJ16[(j*768+o)*768+q].
// ---------------------------------------------------------------------------
__global__ __launch_bounds__(256) void k_wprep2(
    const float* __restrict__ w0, const float* __restrict__ w1,
    const float* __restrict__ w2, const float* __restrict__ w3,
    u16* __restrict__ WJ16) {
  int idx0 = blockIdx.x * 256 + threadIdx.x;
  for (int idx = idx0; idx < 2359296; idx += 256 * 256) {
    int j = idx / 589824;
    int r = idx - j * 589824;
    const float* w = (j == 0) ? w0 : (j == 1) ? w1 : (j == 2) ? w2 : w3;
    WJ16[idx] = f2b(w[r]);
  }
}

// ---------------------------------------------------------------------------
// K1: per-series norm chain, group-fused. One wave/series; 4/block.
// ---------------------------------------------------------------------------
__global__ __launch_bounds__(256) void k1_chain(
    const float* __restrict__ xb, float* __restrict__ ltm, float* __restrict__ lts,
    float* __restrict__ pm, float* __restrict__ ps, u16* __restrict__ stm,
    u16* __restrict__ sts, u16* __restrict__ x3, u16* __restrict__ SG) {
  __shared__ float lds[4 * 352];
  int tid = threadIdx.x;
  int wv = tid >> 6, lane = tid & 63;
  float* buf = lds + wv * 352;
  float* pat = buf + 288;
  long s = (long)blockIdx.x * 4 + wv;
  const float* xs = xb + s * Tx;

  int b_loc = (int)(s >> 13);
  int cin = ((int)s >> 7) & 63;
  int n = (int)s & 127;
  long sg0 = (((long)b_loc * 4) * 128 + n) * 768 + cin * 12;

  float v[5];
  float sum = 0.f, sum2 = 0.f;
#pragma unroll
  for (int i = 0; i < 5; ++i) {
    int t = lane + 64 * i;
    if (t < Tx) { v[i] = xs[t]; sum += v[i]; sum2 += v[i] * v[i]; }
    else v[i] = 0.f;
  }
  for (int off = 32; off; off >>= 1) {
    sum += __shfl_xor(sum, off, 64);
    sum2 += __shfl_xor(sum2, off, 64);
  }
  float mean = sum * (1.f / 288.f);
  float var = sum2 * (1.f / 288.f) - mean * mean + 1e-5f;
  float sd = sqrtf(var);
  float r1 = rsqrtf(var + EPSV);
  if (lane == 0) { ltm[s] = mean; lts[s] = sd; }
#pragma unroll
  for (int i = 0; i < 5; ++i) {
    int t = lane + 64 * i;
    if (t < Tx) {
      float x1v = (v[i] - mean) * r1;
      v[i] = x1v;
      buf[t] = x1v;
      if (t >= Tx - SP) SG[sg0 + t - (Tx - SP)] = f2b(x1v);
    }
  }
  __syncthreads();
  if (lane < CL) {
    float a = 0.f, b2 = 0.f;
    for (int k = 0; k < 12; ++k) {
      float u = buf[k * CL + lane];
      a += u; b2 += u * u;
    }
    float pmv = a * (1.f / 12.f);
    float pvar = b2 * (1.f / 12.f) - pmv * pmv + 1e-5f;
    float psd = sqrtf(pvar);
    pat[lane] = pmv; pat[CL + lane] = psd;
    pm[s * CL + lane] = pmv; ps[s * CL + lane] = psd;
  }
  __syncthreads();
  float w2v[5];
#pragma unroll
  for (int i = 0; i < 5; ++i) {
    int t = lane + 64 * i;
    if (t < Tx) {
      int l = t % CL;
      float pmv = pat[l], psd = pat[CL + l];
      float x2v = (v[i] - pmv) * rsqrtf(psd * psd + EPSV);
      w2v[i] = x2v;
      if (t >= Tx - SP) SG[sg0 + 98304 + t - (Tx - SP)] = f2b(x2v);
    } else w2v[i] = 0.f;
  }
  __syncthreads();
#pragma unroll
  for (int i = 0; i < 5; ++i) {
    int t = lane + 64 * i;
    if (t < Tx) buf[t] = w2v[i];
  }
  __syncthreads();
#pragma unroll
  for (int i = 0; i < 5; ++i) {
    int t = lane + 64 * i;
    if (t < Tx) {
      int te = t < 11 ? 11 : t;
      float a = 0.f, b2 = 0.f;
#pragma unroll
      for (int jj = 0; jj < 12; ++jj) {
        float u = buf[te - 11 + jj];
        a += u; b2 += u * u;
      }
      float m = a * (1.f / 12.f);
      float varw = b2 * (1.f / 12.f) - m * m + 1e-5f;
      stm[s * Tx + t] = f2b(m);
      sts[s * Tx + t] = f2b(sqrtf(varw));
      u16 xb3 = f2b((w2v[i] - m) * rsqrtf(varw + EPSV));
      x3[s * Tx + t] = xb3;
      if (t >= Tx - SP) SG[sg0 + 2 * 98304 + t - (Tx - SP)] = xb3;
    }
  }
}

// ---------------------------------------------------------------------------
// K2 (MFMA): spatial norm. Per block (c, tc): mean = adj @ X, msq = adj @ X^2
// via mfma_f32_16x16x32_bf16, M=128 n x N=32 t x K=128 m.  grid g*576 x 256.
// LDS: Xt/Qt staged [t][m] (pad 136); out transposed [n][40] for uint4 stores.
// ---------------------------------------------------------------------------
__global__ __launch_bounds__(256) void k2_spatial(
    const u16* __restrict__ x3, const u16* __restrict__ adjB,
    u16* __restrict__ x4, u16* __restrict__ spm, u16* __restrict__ sps,
    u16* __restrict__ SG) {
  __shared__ __align__(16) unsigned char sraw[48128];
  u16* Xt = (u16*)sraw;                  // [32][136] bf16
  u16* Qt = (u16*)(sraw + 8704);         // [32][136] bf16 (squares)
  u16* oX = (u16*)(sraw + 17408);        // [128][40]
  u16* oM = (u16*)(sraw + 27648);        // [128][40]
  u16* oS = (u16*)(sraw + 37888);        // [128][40]
  int bid = blockIdx.x;
  int tc = bid % 9;
  long c = bid / 9;
  int t0 = tc * 32;
  int tid = threadIdx.x;
  int wv = tid >> 6, lane = tid & 63;
  int rlane = lane & 15, glane = lane >> 4;
  int klane = glane * 8;

  // ---- stage Xt[t][m] and Qt[t][m]: thread = (m-pair, t-octet) ----
  {
    int mp = tid & 63, tq = tid >> 6;
    const u16* p0 = x3 + (c * 128 + 2 * mp) * Tx + t0 + 8 * tq;
    uint4 a = *(const uint4*)p0;
    uint4 b = *(const uint4*)(p0 + Tx);
    u32 aw[4] = {a.x, a.y, a.z, a.w};
    u32 bw[4] = {b.x, b.y, b.z, b.w};
#pragma unroll
    for (int q = 0; q < 4; ++q) {
#pragma unroll
      for (int h = 0; h < 2; ++h) {
        int t = 8 * tq + q * 2 + h;
        u16 lo = (u16)(aw[q] >> (16 * h));
        u16 hi = (u16)(bw[q] >> (16 * h));
        *(u32*)(Xt + t * 136 + 2 * mp) = (u32)lo | ((u32)hi << 16);
        float fl = b2f(lo), fh = b2f(hi);
        *(u32*)(Qt + t * 136 + 2 * mp) = (u32)f2b(fl * fl) | ((u32)f2b(fh * fh) << 16);
      }
    }
  }
  __syncthreads();

  // ---- MFMA: wave wv -> n rows wv*32..+31; K=128 in 4 steps ----
  f4v am[2][2], aq[2][2];
#pragma unroll
  for (int rt = 0; rt < 2; ++rt)
#pragma unroll
    for (int ct = 0; ct < 2; ++ct) {
#pragma unroll
      for (int reg = 0; reg < 4; ++reg) { am[rt][ct][reg] = 0.f; aq[rt][ct][reg] = 0.f; }
    }
#pragma unroll
  for (int kc = 0; kc < 4; ++kc) {
    s8v av[2], bx[2], bq[2];
#pragma unroll
    for (int rt = 0; rt < 2; ++rt) {
      int R = wv * 32 + rt * 16 + rlane;
      av[rt] = *(const s8v*)(adjB + R * 128 + kc * 32 + klane);
    }
#pragma unroll
    for (int ct = 0; ct < 2; ++ct) {
      int tl = ct * 16 + rlane;
      bx[ct] = *(const s8v*)(Xt + tl * 136 + kc * 32 + klane);
      bq[ct] = *(const s8v*)(Qt + tl * 136 + kc * 32 + klane);
    }
#pragma unroll
    for (int rt = 0; rt < 2; ++rt)
#pragma unroll
      for (int ct = 0; ct < 2; ++ct) {
        am[rt][ct] = __builtin_amdgcn_mfma_f32_16x16x32_bf16(av[rt], bx[ct], am[rt][ct], 0, 0, 0);
        aq[rt][ct] = __builtin_amdgcn_mfma_f32_16x16x32_bf16(av[rt], bq[ct], aq[rt][ct], 0, 0, 0);
      }
  }

  // ---- epilogue: normalize + transpose into out-LDS ----
#pragma unroll
  for (int rt = 0; rt < 2; ++rt)
#pragma unroll
    for (int ct = 0; ct < 2; ++ct) {
      int tl = ct * 16 + rlane;
#pragma unroll
      for (int reg = 0; reg < 4; ++reg) {
        int n = wv * 32 + rt * 16 + glane * 4 + reg;
        float mean = am[rt][ct][reg];
        float varv = aq[rt][ct][reg] - mean * mean + 1e-5f;
        float xv = b2f(Xt[tl * 136 + n]);
        oX[n * 40 + tl] = f2b((xv - mean) * rsqrtf(varv + EPSV));
        oM[n * 40 + tl] = f2b(mean);
        oS[n * 40 + tl] = f2b(sqrtf(varv));
      }
    }
  __syncthreads();

  // ---- coalesced stores: thread = (n, half of 16 t) ----
  {
    int n2 = tid >> 1, half = tid & 1;
    long basei = (c * 128 + n2) * Tx + t0 + half * 16;
    uint4 v0 = *(const uint4*)(oX + n2 * 40 + half * 16);
    uint4 v1 = *(const uint4*)(oX + n2 * 40 + half * 16 + 8);
    *(uint4*)(x4 + basei) = v0;
    *(uint4*)(x4 + basei + 8) = v1;
    v0 = *(const uint4*)(oM + n2 * 40 + half * 16);
    v1 = *(const uint4*)(oM + n2 * 40 + half * 16 + 8);
    *(uint4*)(spm + basei) = v0;
    *(uint4*)(spm + basei + 8) = v1;
    v0 = *(const uint4*)(oS + n2 * 40 + half * 16);
    v1 = *(const uint4*)(oS + n2 * 40 + half * 16 + 8);
    *(uint4*)(sps + basei) = v0;
    *(uint4*)(sps + basei + 8) = v1;
    if (tc == 8 && half == 1) {   // t = 276..287 -> tl 20..31
      long sg = (((c >> 6) * 4 + 3) * 128 + n2) * 768 + (long)(c & 63) * 12;
      u32* sp = (u32*)(SG + sg);
      const u32* src = (const u32*)(oX + n2 * 40 + 20);
#pragma unroll
      for (int k = 0; k < 6; ++k) sp[k] = src[k];
    }
  }
}

// ---------------------------------------------------------------------------
// K3 (MFMA): tails GEMM. Per (b_loc,j): out[128n][768o] = S[n][q] . W[o][q] + b.
// ---------------------------------------------------------------------------
__global__ __launch_bounds__(256) void k3_mfma(
    const u16* __restrict__ SG, const u16* __restrict__ WJ16,
    const float* __restrict__ bb0, const float* __restrict__ bb1,
    const float* __restrict__ bb2, const float* __restrict__ bb3,
    u16* __restrict__ tails) {
  __shared__ u16 Al[64 * 40];
  __shared__ u16 Bl[128 * 40];
  int bid = blockIdx.x;
  int ot = bid % 6;
  int rest = bid / 6;
  int nt = rest & 1;
  int bj = rest >> 1;            // b_loc*4 + j
  int j = bj & 3;
  int tid = threadIdx.x;
  int wv = tid >> 6, lane = tid & 63;
  int wo = wv & 1, wm = wv >> 1;
  int rlane = lane & 15, glane = lane >> 4;
  int klane = glane * 8;

  const float* Bv = (j == 0) ? bb0 : (j == 1) ? bb1 : (j == 2) ? bb2 : bb3;
  const u16* Abase = SG + (long)bj * 98304 + (long)(nt * 64) * 768;
  const u16* Wbase = WJ16 + (long)j * 589824 + (long)(ot * 128) * 768;

  f4v acc[2][4];
#pragma unroll
  for (int ct = 0; ct < 4; ++ct) {
    float bvv = Bv[ot * 128 + wo * 64 + ct * 16 + rlane];
#pragma unroll
    for (int rt = 0; rt < 2; ++rt)
#pragma unroll
      for (int reg = 0; reg < 4; ++reg) acc[rt][ct][reg] = bvv;
  }

  int srow = tid >> 2, sseg = tid & 3;     // staging assignment
  for (int ks = 0; ks < 24; ++ks) {
    int q0 = ks * 32;
    __syncthreads();
    *(float4*)(Al + srow * 40 + sseg * 8) =
        *(const float4*)(Abase + (long)srow * 768 + q0 + sseg * 8);
    *(float4*)(Bl + srow * 40 + sseg * 8) =
        *(const float4*)(Wbase + (long)srow * 768 + q0 + sseg * 8);
    *(float4*)(Bl + (srow + 64) * 40 + sseg * 8) =
        *(const float4*)(Wbase + (long)(srow + 64) * 768 + q0 + sseg * 8);
    __syncthreads();
    s8v av[2], bv[4];
#pragma unroll
    for (int rt = 0; rt < 2; ++rt)
      av[rt] = *(const s8v*)(Al + (wm * 32 + rt * 16 + rlane) * 40 + klane);
#pragma unroll
    for (int ct = 0; ct < 4; ++ct)
      bv[ct] = *(const s8v*)(Bl + (wo * 64 + ct * 16 + rlane) * 40 + klane);
#pragma unroll
    for (int rt = 0; rt < 2; ++rt)
#pragma unroll
      for (int ct = 0; ct < 4; ++ct)
        acc[rt][ct] = __builtin_amdgcn_mfma_f32_16x16x32_bf16(av[rt], bv[ct], acc[rt][ct], 0, 0, 0);
  }

  long outbase = (long)bj * 98304;  // 128*768 per (b,j)
#pragma unroll
  for (int rt = 0; rt < 2; ++rt) {
    int nn = nt * 64 + wm * 32 + rt * 16 + glane * 4;
#pragma unroll
    for (int ct = 0; ct < 4; ++ct) {
      int o = ot * 128 + wo * 64 + ct * 16 + rlane;
#pragma unroll
      for (int reg = 0; reg < 4; ++reg)
        tails[outbase + (long)(nn + reg) * 768 + o] = f2b(acc[rt][ct][reg]);
    }
  }
}

// ---------------------------------------------------------------------------
// Staging for k4 (SINGLE-TAP layout): Bs[u][cc], stride 72 u16, u in 0..32,
// value = xcat[j][cc][t0-1+u].  MFMA reads row tl (tap0) and tl+1 (tap1).
// Round-8 proven form: rolled loop, scalar eval per element, 36 VGPR.
// ---------------------------------------------------------------------------
template<int MODE>
__device__ __forceinline__ void stage_one(
    u16* __restrict__ Bb, const u16* __restrict__ T,
    const float* __restrict__ Tf, const float* __restrict__ fm,
    const float* __restrict__ fs, const float* __restrict__ fpm,
    const float* __restrict__ fps, const u16* __restrict__ tl,
    int n, int t0, int ccp, int u) {
  int cc0 = ccp * 2;
  int tg = t0 - 1 + u;
  u32 w = 0;
  if (MODE == 0) {
    if ((unsigned)tg < (unsigned)TOUT) {
      int tcl = tg < Tx ? tg : Tx - 1;
      const u16* p = T + ((long)cc0 * 128 + n) * Tx + tcl;
      w = (u32)p[0] | ((u32)p[128 * Tx] << 16);
    }
  } else if (MODE == 1) {
    if ((unsigned)tg < (unsigned)Tx) {
      const u16* p = T + ((long)cc0 * 128 + n) * Tx + tg;
      w = (u32)p[0] | ((u32)p[128 * Tx] << 16);
    } else if (tg >= Tx && tg < TOUT) {
      w = *(const u32*)(tl + (long)n * 768 + (tg - Tx) * 64 + cc0);
    }
  } else if (MODE == 2) {
    if ((unsigned)tg < (unsigned)TOUT)
      w = (u32)f2b(Tf[cc0 * 128 + n]) | ((u32)f2b(Tf[(cc0 + 1) * 128 + n]) << 16);
  } else if (MODE == 3) {
    if ((unsigned)tg < (unsigned)TOUT) {
      int l = tg % CL;
      w = (u32)f2b(Tf[((long)cc0 * 128 + n) * CL + l]) |
          ((u32)f2b(Tf[((long)(cc0 + 1) * 128 + n) * CL + l]) << 16);
    }
  } else if (MODE == 4) {
    if ((unsigned)tg < (unsigned)TOUT) {
      int tcl = tg < Tx ? tg : Tx - 1;
      const float* p = Tf + ((long)cc0 * 128 + n) * Tx + tcl;
      w = (u32)f2b(p[0]) | ((u32)f2b(p[128 * Tx]) << 16);
    }
  } else if (MODE == 5) {
    if ((unsigned)tg < (unsigned)Tx) {
      long s0 = (long)cc0 * 128 + n, s1 = s0 + 128;
      float v0 = (Tf[s0 * Tx + tg] - fm[s0]) * rsqrtf(fs[s0] * fs[s0] + EPSV);
      float v1 = (Tf[s1 * Tx + tg] - fm[s1]) * rsqrtf(fs[s1] * fs[s1] + EPSV);
      w = (u32)f2b(v0) | ((u32)f2b(v1) << 16);
    } else if (tg >= Tx && tg < TOUT) {
      w = *(const u32*)(tl + (long)n * 768 + (tg - Tx) * 64 + cc0);
    }
  } else {  // MODE 6
    if ((unsigned)tg < (unsigned)Tx) {
      long s0 = (long)cc0 * 128 + n, s1 = s0 + 128;
      int l = tg % CL;
      float x10 = (Tf[s0 * Tx + tg] - fm[s0]) * rsqrtf(fs[s0] * fs[s0] + EPSV);
      float x11 = (Tf[s1 * Tx + tg] - fm[s1]) * rsqrtf(fs[s1] * fs[s1] + EPSV);
      float p0 = fpm[s0 * CL + l], q0 = fps[s0 * CL + l];
      float p1 = fpm[s1 * CL + l], q1 = fps[s1 * CL + l];
      float v0 = (x10 - p0) * rsqrtf(q0 * q0 + EPSV);
      float v1 = (x11 - p1) * rsqrtf(q1 * q1 + EPSV);
      w = (u32)f2b(v0) | ((u32)f2b(v1) << 16);
    } else if (tg >= Tx && tg < TOUT) {
      w = *(const u32*)(tl + (long)n * 768 + (tg - Tx) * 64 + cc0);
    }
  }
  *(u32*)(Bb + u * 72 + cc0) = w;
}

// ROLLED loop (pragma unroll 1): one body copy -> low VGPR pressure.
template<int MODE>
__device__ __forceinline__ void stage_j(
    u16* __restrict__ Bb, const u16* __restrict__ T,
    const float* __restrict__ Tf, const float* __restrict__ fm,
    const float* __restrict__ fs, const float* __restrict__ fpm,
    const float* __restrict__ fps, const u16* __restrict__ tl,
    int n, int t0, int tid) {
#pragma unroll 1
  for (int idx = tid; idx < 1056; idx += 256) {  // 32 ccp x 33 u
    int ccp = idx / 33;
    int u = idx - ccp * 33;
    stage_one<MODE>(Bb, T, Tf, fm, fs, fpm, fps, tl, n, t0, ccp, u);
  }
}

// ---------------------------------------------------------------------------
// K4 (MFMA), group-fused: M=128 rows x N=32 t x K=1664 per block + epilogue.
// Round-8 proven config: rolled staging, acc 16 f32/thread, LDS 9504 B.
// ---------------------------------------------------------------------------
__global__ __launch_bounds__(256) void k4_mfma(
    const float* __restrict__ xbG, const float* __restrict__ ltmG,
    const float* __restrict__ ltsG, const float* __restrict__ pmG,
    const float* __restrict__ psG, const u16* __restrict__ stmG,
    const u16* __restrict__ stsG, const u16* __restrict__ x3G,
    const u16* __restrict__ x4G, const u16* __restrict__ spmG,
    const u16* __restrict__ spsG, const u16* __restrict__ tailsG,
    const u16* __restrict__ W16, const u16* __restrict__ WR16,
    const u16* __restrict__ WS16, const float* __restrict__ cb1,
    const float* __restrict__ cb2, const float* __restrict__ rsb,
    const float* __restrict__ skb,
    float* __restrict__ outXZG, float* __restrict__ outSG) {
  __shared__ __align__(16) unsigned char smemraw[9504];
  u16* Bs0 = (u16*)smemraw;                  // [33][72] bf16 (4752 B)
  u16* Bs1 = (u16*)(smemraw + 4752);         // [33][72] bf16
  u16* abuf = (u16*)smemraw;                 // epilogue [64][36] bf16 (4608 B)
  u16* zB = (u16*)(smemraw + 4608);          // epilogue [32][72] bf16 (4608 B)

  int bid = blockIdx.x;
  int n = bid & 127;
  int q = bid >> 7;
  int b_loc = q / 10;
  int chunk = q - b_loc * 10;                // 0..9
  int t0 = chunk * 32;
  int tid = threadIdx.x;
  int wv = tid >> 6, lane = tid & 63;
  int rlane = lane & 15, glane = lane >> 4;
  int klane = glane * 8;

  const float* xb  = xbG + b_loc * NTb;
  const float* ltm = ltmG + (long)b_loc * 8192;
  const float* lts = ltsG + (long)b_loc * 8192;
  const float* pm  = pmG + (long)b_loc * 196608;
  const float* ps  = psG + (long)b_loc * 196608;
  const u16* stm = stmG + b_loc * NTb;
  const u16* sts = stsG + b_loc * NTb;
  const u16* x3  = x3G + b_loc * NTb;
  const u16* x4  = x4G + b_loc * NTb;
  const u16* spm = spmG + b_loc * NTb;
  const u16* sps = spsG + b_loc * NTb;
  const u16* tails = tailsG + (long)b_loc * 393216;
  float* outXZ = outXZG + b_loc * NTb;
  float* outS  = outSG + (long)b_loc * 8192 * PL;

  f4v acc[2][2];
#pragma unroll
  for (int rt = 0; rt < 2; ++rt) {
    int Rb = wv * 32 + rt * 16 + glane * 4;
#pragma unroll
    for (int reg = 0; reg < 4; ++reg) {
      int R = Rb + reg;
      float bv = (R < 64) ? cb1[R] : cb2[R - 64];
#pragma unroll
      for (int ct = 0; ct < 2; ++ct) acc[rt][ct][reg] = bv;
    }
  }

  u16* bs = Bs0;
  u16* bo = Bs1;
  // prologue: stage j=0 (xb, f32 path)
  stage_j<4>(bs, (const u16*)0, xb, 0, 0, 0, 0, (const u16*)0, n, t0, tid);

  for (int j = 0; j < 13; ++j) {
    __syncthreads();
    // stage next j into the other buffer (overlaps with MFMA below)
    switch (j + 1) {
      case 1:  stage_j<5>(bo, 0, xb, ltm, lts, 0, 0, tails, n, t0, tid); break;
      case 2:  stage_j<2>(bo, 0, ltm, 0, 0, 0, 0, 0, n, t0, tid); break;
      case 3:  stage_j<2>(bo, 0, lts, 0, 0, 0, 0, 0, n, t0, tid); break;
      case 4:  stage_j<6>(bo, 0, xb, ltm, lts, pm, ps, tails + 98304, n, t0, tid); break;
      case 5:  stage_j<3>(bo, 0, pm, 0, 0, 0, 0, 0, n, t0, tid); break;
      case 6:  stage_j<3>(bo, 0, ps, 0, 0, 0, 0, 0, n, t0, tid); break;
      case 7:  stage_j<1>(bo, x3, 0, 0, 0, 0, 0, tails + 2 * 98304, n, t0, tid); break;
      case 8:  stage_j<0>(bo, stm, 0, 0, 0, 0, 0, 0, n, t0, tid); break;
      case 9:  stage_j<0>(bo, sts, 0, 0, 0, 0, 0, 0, n, t0, tid); break;
      case 10: stage_j<1>(bo, x4, 0, 0, 0, 0, 0, tails + 3 * 98304, n, t0, tid); break;
      case 11: stage_j<0>(bo, spm, 0, 0, 0, 0, 0, 0, n, t0, tid); break;
      case 12: stage_j<0>(bo, sps, 0, 0, 0, 0, 0, 0, n, t0, tid); break;
      default: break;                        // j==12: nothing left to stage
    }
    // MFMA on current buffer: kc 0,1 = tap0 (row tl), kc 2,3 = tap1 (row tl+1)
#pragma unroll
    for (int kc = 0; kc < 4; ++kc) {
      const u16* wj = W16 + (j * 4 + kc) * 4096;
      s8v av[2], bv[2];
#pragma unroll
      for (int rt = 0; rt < 2; ++rt) {
        int R = wv * 32 + rt * 16 + rlane;
        av[rt] = *(const s8v*)(wj + R * 32 + klane);
      }
#pragma unroll
      for (int ct = 0; ct < 2; ++ct) {
        int row = ct * 16 + rlane + (kc >> 1);
        bv[ct] = *(const s8v*)(bs + row * 72 + (kc & 1) * 32 + klane);
      }
#pragma unroll
      for (int rt = 0; rt < 2; ++rt)
#pragma unroll
        for (int ct = 0; ct < 2; ++ct)
          acc[rt][ct] = __builtin_amdgcn_mfma_f32_16x16x32_bf16(av[rt], bv[ct], acc[rt][ct], 0, 0, 0);
    }
    u16* tsw = bs; bs = bo; bo = tsw;
  }

  // ---- epilogue: waves 2,3 hold conv2 rows -> abuf (bf16); waves 0,1 make z ----
  __syncthreads();
  if (wv >= 2) {
#pragma unroll
    for (int rt = 0; rt < 2; ++rt)
#pragma unroll
      for (int ct = 0; ct < 2; ++ct)
#pragma unroll
        for (int reg = 0; reg < 4; ++reg) {
          int r = (wv - 2) * 32 + rt * 16 + glane * 4 + reg;
          int tl2 = ct * 16 + rlane;
          abuf[r * 36 + tl2] = f2b(acc[rt][ct][reg]);
        }
  }
  __syncthreads();
  if (wv < 2) {
#pragma unroll
    for (int rt = 0; rt < 2; ++rt)
#pragma unroll
      for (int ct = 0; ct < 2; ++ct)
#pragma unroll
        for (int reg = 0; reg < 4; ++reg) {
          int r = wv * 32 + rt * 16 + glane * 4 + reg;
          int tl2 = ct * 16 + rlane;
          float a2v = b2f(abuf[r * 36 + tl2]);
          float z = tanhf(acc[rt][ct][reg]) * (1.f / (1.f + expf(-a2v)));
          zB[tl2 * 72 + r] = f2b(z);
        }
  }
  __syncthreads();
  {
    int oL = wv * 16 + rlane;
    int oS = wv * 16 + glane * 4;
    s8v aR0 = *(const s8v*)(WR16 + oL * 32 + klane);
    s8v aR1 = *(const s8v*)(WR16 + 2048 + oL * 32 + klane);
    s8v aS0 = *(const s8v*)(WS16 + oL * 32 + klane);
    s8v aS1 = *(const s8v*)(WS16 + 2048 + oL * 32 + klane);
    for (int tt = 0; tt < 2; ++tt) {
      int tstart = t0 + tt * 16;
      if (tstart >= TOUT) break;
      bool res = tstart < Tx;
      s8v b0 = *(const s8v*)(zB + (tt * 16 + rlane) * 72 + klane);
      s8v b1 = *(const s8v*)(zB + (tt * 16 + rlane) * 72 + 32 + klane);
      f4v oa;
#pragma unroll
      for (int reg = 0; reg < 4; ++reg)
        oa[reg] = res ? rsb[oS + reg] : skb[oS + reg];
      if (res) {
        oa = __builtin_amdgcn_mfma_f32_16x16x32_bf16(aR0, b0, oa, 0, 0, 0);
        oa = __builtin_amdgcn_mfma_f32_16x16x32_bf16(aR1, b1, oa, 0, 0, 0);
        int tglob = tstart + rlane;
#pragma unroll
        for (int reg = 0; reg < 4; ++reg)
          outXZ[((long)(oS + reg) * 128 + n) * Tx + tglob] = oa[reg];
      } else {
        oa = __builtin_amdgcn_mfma_f32_16x16x32_bf16(aS0, b0, oa, 0, 0, 0);
        oa = __builtin_amdgcn_mfma_f32_16x16x32_bf16(aS1, b1, oa, 0, 0, 0);
        int tglob = tstart + rlane;
        if (tglob < TOUT) {
#pragma unroll
          for (int reg = 0; reg < 4; ++reg)
            outS[((long)(oS + reg) * 128 + n) * PL + (tglob - Tx)] = oa[reg];
        }
      }
    }
  }
}

// ---------------------------------------------------------------------------
extern "C" void kernel_launch(void* const* d_in, const int* in_sizes, int n_in,
                              void* d_out, int out_size, void* d_ws, size_t ws_size,
                              hipStream_t stream) {
  const float* x   = (const float*)d_in[0];
  const float* emb = (const float*)d_in[1];
  const float* rew[4] = {(const float*)d_in[2], (const float*)d_in[4],
                         (const float*)d_in[6], (const float*)d_in[8]};
  const float* reb[4] = {(const float*)d_in[3], (const float*)d_in[5],
                         (const float*)d_in[7], (const float*)d_in[9]};
  const float* c1w = (const float*)d_in[10];
  const float* c1b = (const float*)d_in[11];
  const float* c2w = (const float*)d_in[12];
  const float* c2b = (const float*)d_in[13];
  const float* skw = (const float*)d_in[14];
  const float* skb = (const float*)d_in[15];
  const float* rsw = (const float*)d_in[16];
  const float* rsb = (const float*)d_in[17];
  float* out = (float*)d_out;

  // shared region: adjB 64KB slot + W16 416KB + WR/WS 16KB + WJ16 4.5MB
  const size_t shared_bytes = 65536 + (52 * 4096 + 2 * 4096) * 2 + 2359296UL * 2;
  // per-batch: f32 409600*4 + u16 (786432 + 6*NTb)*2 = 31,522,816 B
  const size_t per_batch = 409600UL * 4 + (786432UL + 6UL * 2359296UL) * 2;
  int g = 1;
  if (shared_bytes + 8 * per_batch + 4096 <= ws_size) g = 8;
  else if (shared_bytes + 4 * per_batch + 4096 <= ws_size) g = 4;
  else if (shared_bytes + 2 * per_batch + 4096 <= ws_size) g = 2;

  float* ws = (float*)d_ws;
  u16* adjB = (u16*)ws;                     // 16384 u16 used (64KB slot kept)
  u16* W16  = (u16*)(ws + 16384);           // 52*4096 u16
  u16* WR16 = W16 + 52 * 4096;              // 4096 u16
  u16* WS16 = WR16 + 4096;                  // 4096 u16
  u16* WJ16 = WS16 + 4096;                  // 4*768*768 u16
  float* fbase = (float*)(WJ16 + 2359296);
  float* ltm = fbase;                       // g*8192
  float* lts = ltm + (long)g * 8192;
  float* pmv = lts + (long)g * 8192;        // g*196608
  float* psv = pmv + (long)g * 196608;
  u16* tails16 = (u16*)(psv + (long)g * 196608);  // g*393216 u16
  u16* SGb = tails16 + (long)g * 393216;          // g*393216 u16
  u16* stm = SGb + (long)g * 393216;        // g*NTb each from here
  u16* sts = stm + (long)g * NTb;
  u16* x3  = sts + (long)g * NTb;
  u16* x4  = x3 + (long)g * NTb;
  u16* spm = x4 + (long)g * NTb;
  u16* sps = spm + (long)g * NTb;

  hipLaunchKernelGGL(k0_adj, dim3(128), dim3(64), 0, stream, emb, adjB);
  hipLaunchKernelGGL(k_wprep, dim3(128), dim3(256), 0, stream,
                     c1w, c2w, rsw, skw, W16, WR16, WS16);
  hipLaunchKernelGGL(k_wprep2, dim3(256), dim3(256), 0, stream,
                     rew[0], rew[1], rew[2], rew[3], WJ16);
  int ng = 8 / g;
  for (int gi = 0; gi < ng; ++gi) {
    long base = (long)gi * g;
    const float* xg = x + base * NTb;
    float* oXZ = out + base * NTb;
    float* oS  = out + (long)Bx * NTb + base * 8192 * PL;
    hipLaunchKernelGGL(k1_chain, dim3(g * 2048), dim3(256), 0, stream,
                       xg, ltm, lts, pmv, psv, stm, sts, x3, SGb);
    hipLaunchKernelGGL(k2_spatial, dim3(g * 576), dim3(256), 0, stream,
                       x3, adjB, x4, spm, sps, SGb);
    hipLaunchKernelGGL(k3_mfma, dim3(g * 48), dim3(256), 0, stream,
                       SGb, WJ16, reb[0], reb[1], reb[2], reb[3], tails16);
    hipLaunchKernelGGL(k4_mfma, dim3(g * 1280), dim3(256), 0, stream,
                       xg, ltm, lts, pmv, psv, stm, sts, x3, x4, spm, sps,
                       tails16, W16, WR16, WS16, c1b, c2b, rsb, skb, oXZ, oS);
  }
}